// Round 1
// baseline (4690.751 us; speedup 1.0000x reference)
//
#include <hip/hip_runtime.h>

#define BETA 0.8f
#define D 256  // message_length (in_sizes[0]/in_sizes[1] == 256 for this problem)

// ---- Pass 1: per-segment max timestamp via unsigned atomicMax -------------
// All timestamps >= 0, so the IEEE-754 bit pattern is monotone under unsigned
// compare. Empty segments keep the memset value 0, which equals the
// reference's where(tw>0, last_t, 0) output for empty segments.
__global__ void seg_max_kernel(const float* __restrict__ ts,
                               const int* __restrict__ node,
                               unsigned int* __restrict__ last_t_bits,
                               int N) {
    int i = blockIdx.x * blockDim.x + threadIdx.x;
    if (i < N) {
        atomicMax(&last_t_bits[node[i]], __float_as_uint(ts[i]));
    }
}

// ---- Pass 2: weighted accumulate ------------------------------------------
// One 64-lane wave per message row. Lane l loads float4 at columns [4l,4l+4),
// scales by w, atomicAdds into wsum[node]. Lane 0 adds w into tw[node].
__global__ void accum_kernel(const float* __restrict__ msgs,
                             const float* __restrict__ ts,
                             const int* __restrict__ node,
                             const unsigned int* __restrict__ last_t_bits,
                             float* __restrict__ wsum,   // [S, D] (agg region of d_out)
                             float* __restrict__ tw,     // [S]
                             int N) {
    int gid  = blockIdx.x * blockDim.x + threadIdx.x;
    int msg  = gid >> 6;          // wave index == message index
    int lane = threadIdx.x & 63;
    if (msg >= N) return;

    int   s  = node[msg];
    float t  = ts[msg];
    float lt = __uint_as_float(last_t_bits[s]);
    float w  = __expf(BETA * (t - lt));   // in (0, 1]; max element gets 1

    const float4* row = (const float4*)(msgs + (size_t)msg * D);
    float4 m = row[lane];

    float* dst = wsum + (size_t)s * D + lane * 4;
    atomicAdd(dst + 0, m.x * w);
    atomicAdd(dst + 1, m.y * w);
    atomicAdd(dst + 2, m.z * w);
    atomicAdd(dst + 3, m.w * w);

    if (lane == 0) atomicAdd(&tw[s], w);
}

// ---- Pass 3: finalize ------------------------------------------------------
// Wave per segment: scale agg in place by 1/tw (0 if empty), write last_t_out.
__global__ void finalize_kernel(float* __restrict__ agg,            // [S, D]
                                const float* __restrict__ tw,       // [S]
                                const unsigned int* __restrict__ last_t_bits,
                                float* __restrict__ last_t_out,     // [S]
                                int S) {
    int gid  = blockIdx.x * blockDim.x + threadIdx.x;
    int seg  = gid >> 6;
    int lane = threadIdx.x & 63;
    if (seg >= S) return;

    float twv   = tw[seg];
    float scale = (twv > 0.0f) ? 1.0f / fmaxf(twv, 1e-30f) : 0.0f;

    float4* row = (float4*)(agg + (size_t)seg * D);
    float4 m = row[lane];
    m.x *= scale; m.y *= scale; m.z *= scale; m.w *= scale;
    row[lane] = m;

    if (lane == 0) {
        last_t_out[seg] = (twv > 0.0f) ? __uint_as_float(last_t_bits[seg]) : 0.0f;
    }
}

extern "C" void kernel_launch(void* const* d_in, const int* in_sizes, int n_in,
                              void* d_out, int out_size, void* d_ws, size_t ws_size,
                              hipStream_t stream) {
    const float* msgs = (const float*)d_in[0];
    const float* ts   = (const float*)d_in[1];
    const int*   node = (const int*)d_in[2];
    // d_in[3] is num_segments on device; recover S from out_size = S*D + S.
    const int N = in_sizes[1];
    const int S = out_size / (D + 1);

    float*        agg        = (float*)d_out;           // [S, D]
    float*        last_t_out = (float*)d_out + (size_t)S * D;  // [S]
    unsigned int* last_t_bits = (unsigned int*)d_ws;    // [S]
    float*        tw          = (float*)((char*)d_ws + (size_t)S * sizeof(unsigned int)); // [S]

    // Zero the accumulators (harness poisons d_out/d_ws with 0xAA each call).
    hipMemsetAsync(d_ws, 0, (size_t)S * 2 * sizeof(unsigned int), stream);
    hipMemsetAsync(d_out, 0, (size_t)S * D * sizeof(float), stream);

    // Pass 1: segment max
    seg_max_kernel<<<(N + 255) / 256, 256, 0, stream>>>(ts, node, last_t_bits, N);

    // Pass 2: weighted accumulate — one wave (64 lanes) per message
    {
        long long waves  = N;
        long long blocks = (waves * 64 + 255) / 256;
        accum_kernel<<<(int)blocks, 256, 0, stream>>>(msgs, ts, node, last_t_bits,
                                                      agg, tw, N);
    }

    // Pass 3: finalize — one wave per segment
    {
        long long waves  = S;
        long long blocks = (waves * 64 + 255) / 256;
        finalize_kernel<<<(int)blocks, 256, 0, stream>>>(agg, tw, last_t_bits,
                                                         last_t_out, S);
    }
}

// Round 2
// 1699.594 us; speedup vs baseline: 2.7599x; 2.7599x over previous
//
#include <hip/hip_runtime.h>

#define BETA 0.8f
#define D 256        // message_length
#define SCAN_T 1024  // scan kernel block size

// ---- Pass 1: histogram of node ids ----------------------------------------
__global__ void hist_kernel(const int* __restrict__ node,
                            int* __restrict__ counts, int N) {
    int i = blockIdx.x * blockDim.x + threadIdx.x;
    if (i < N) atomicAdd(&counts[node[i]], 1);
}

// ---- Pass 2: exclusive scan over counts[S] (single workgroup) -------------
// S = 65536, SCAN_T = 1024 threads, each thread scans a contiguous chunk.
__global__ void scan_kernel(const int* __restrict__ counts,
                            int* __restrict__ offsets,
                            int* __restrict__ cursor, int S) {
    __shared__ int sums[SCAN_T];
    int tid   = threadIdx.x;
    int chunk = (S + SCAN_T - 1) / SCAN_T;
    int base  = tid * chunk;

    int s = 0;
    for (int i = 0; i < chunk; ++i) {
        int j = base + i;
        if (j < S) s += counts[j];
    }
    sums[tid] = s;
    __syncthreads();

    // Hillis-Steele inclusive scan over thread sums
    for (int off = 1; off < SCAN_T; off <<= 1) {
        int v = 0;
        if (tid >= off) v = sums[tid - off];
        __syncthreads();
        if (tid >= off) sums[tid] += v;
        __syncthreads();
    }

    int run = (tid > 0) ? sums[tid - 1] : 0;
    for (int i = 0; i < chunk; ++i) {
        int j = base + i;
        if (j < S) {
            offsets[j] = run;
            cursor[j]  = run;
            run += counts[j];
        }
    }
}

// ---- Pass 3: scatter message indices into segment buckets -----------------
__global__ void scatter_kernel(const int* __restrict__ node,
                               int* __restrict__ cursor,
                               int* __restrict__ sorted, int N) {
    int i = blockIdx.x * blockDim.x + threadIdx.x;
    if (i < N) {
        int pos = atomicAdd(&cursor[node[i]], 1);
        sorted[pos] = i;
    }
}

// ---- Pass 4: fused per-segment reduction ----------------------------------
// One 64-lane wave per segment. Lane l owns columns [4l, 4l+4) as a float4.
// Loop 1 over the bucket finds max timestamp; loop 2 accumulates weighted
// sum + total weight in registers; single scaled write. No output atomics,
// no separate finalize, empty segments write zeros.
__global__ void reduce_kernel(const float* __restrict__ msgs,
                              const float* __restrict__ ts,
                              const int* __restrict__ sorted,
                              const int* __restrict__ offsets,
                              const int* __restrict__ counts,
                              float* __restrict__ agg,        // [S, D]
                              float* __restrict__ last_t_out, // [S]
                              int S) {
    int gid  = blockIdx.x * blockDim.x + threadIdx.x;
    int seg  = gid >> 6;
    int lane = threadIdx.x & 63;
    if (seg >= S) return;

    float4* orow = (float4*)(agg + (size_t)seg * D);
    int cnt = counts[seg];
    if (cnt == 0) {
        orow[lane] = make_float4(0.f, 0.f, 0.f, 0.f);
        if (lane == 0) last_t_out[seg] = 0.0f;
        return;
    }
    int start = offsets[seg];

    // loop 1: segment max timestamp (broadcast loads, L2-resident arrays)
    float maxt = -1e30f;
    for (int r = 0; r < cnt; ++r) {
        int idx = sorted[start + r];
        maxt = fmaxf(maxt, ts[idx]);
    }

    // loop 2: weighted accumulate
    float4 acc = make_float4(0.f, 0.f, 0.f, 0.f);
    float  tw  = 0.0f;
    for (int r = 0; r < cnt; ++r) {
        int   idx = sorted[start + r];
        float w   = __expf(BETA * (ts[idx] - maxt));  // in (0, 1], ==1 for max elem
        const float4* row = (const float4*)(msgs + (size_t)idx * D);
        float4 m = row[lane];
        acc.x += m.x * w;
        acc.y += m.y * w;
        acc.z += m.z * w;
        acc.w += m.w * w;
        tw    += w;
    }

    float inv = 1.0f / tw;  // tw >= 1: the max element contributes exp(0)=1
    orow[lane] = make_float4(acc.x * inv, acc.y * inv, acc.z * inv, acc.w * inv);
    if (lane == 0) last_t_out[seg] = maxt;
}

extern "C" void kernel_launch(void* const* d_in, const int* in_sizes, int n_in,
                              void* d_out, int out_size, void* d_ws, size_t ws_size,
                              hipStream_t stream) {
    const float* msgs = (const float*)d_in[0];
    const float* ts   = (const float*)d_in[1];
    const int*   node = (const int*)d_in[2];
    const int N = in_sizes[1];
    const int S = out_size / (D + 1);   // out = [S*D agg] + [S last_t]

    float* agg        = (float*)d_out;                      // [S, D]
    float* last_t_out = (float*)d_out + (size_t)S * D;      // [S]

    // workspace layout: counts[S] | offsets[S] | cursor[S] | sorted[N]
    int* counts  = (int*)d_ws;
    int* offsets = counts + S;
    int* cursor  = offsets + S;
    int* sorted  = cursor + S;

    hipMemsetAsync(counts, 0, (size_t)S * sizeof(int), stream);

    hist_kernel<<<(N + 255) / 256, 256, 0, stream>>>(node, counts, N);
    scan_kernel<<<1, SCAN_T, 0, stream>>>(counts, offsets, cursor, S);
    scatter_kernel<<<(N + 255) / 256, 256, 0, stream>>>(node, cursor, sorted, N);

    long long threads = (long long)S * 64;
    reduce_kernel<<<(int)((threads + 255) / 256), 256, 0, stream>>>(
        msgs, ts, sorted, offsets, counts, agg, last_t_out, S);
}

// Round 3
// 1625.422 us; speedup vs baseline: 2.8859x; 1.0456x over previous
//
#include <hip/hip_runtime.h>

#define BETA 0.8f
#define D 256        // message_length
#define SCAN_T 1024  // scan kernel block size

// ---- Pass 1: histogram of node ids ----------------------------------------
__global__ void hist_kernel(const int* __restrict__ node,
                            int* __restrict__ counts, int N) {
    int i = blockIdx.x * blockDim.x + threadIdx.x;
    if (i < N) atomicAdd(&counts[node[i]], 1);
}

// ---- Pass 2: exclusive scan over counts[S] (single workgroup) -------------
__global__ void scan_kernel(const int* __restrict__ counts,
                            int* __restrict__ offsets,
                            int* __restrict__ cursor, int S) {
    __shared__ int sums[SCAN_T];
    int tid   = threadIdx.x;
    int chunk = (S + SCAN_T - 1) / SCAN_T;
    int base  = tid * chunk;

    int s = 0;
    for (int i = 0; i < chunk; ++i) {
        int j = base + i;
        if (j < S) s += counts[j];
    }
    sums[tid] = s;
    __syncthreads();

    for (int off = 1; off < SCAN_T; off <<= 1) {
        int v = 0;
        if (tid >= off) v = sums[tid - off];
        __syncthreads();
        if (tid >= off) sums[tid] += v;
        __syncthreads();
    }

    int run = (tid > 0) ? sums[tid - 1] : 0;
    for (int i = 0; i < chunk; ++i) {
        int j = base + i;
        if (j < S) {
            offsets[j] = run;
            cursor[j]  = run;
            run += counts[j];
        }
    }
}

// ---- Pass 3: scatter message indices AND timestamps into buckets ----------
// Writing sorted_t here turns the reduce kernel's dependent ts[idx] gather
// into a coalesced lane-parallel load.
__global__ void scatter_kernel(const int* __restrict__ node,
                               const float* __restrict__ ts,
                               int* __restrict__ cursor,
                               int* __restrict__ sorted,
                               float* __restrict__ sorted_t, int N) {
    int i = blockIdx.x * blockDim.x + threadIdx.x;
    if (i < N) {
        int pos = atomicAdd(&cursor[node[i]], 1);
        sorted[pos]   = i;
        sorted_t[pos] = ts[i];
    }
}

// ---- Pass 4: fused per-segment reduction, latency-optimized ---------------
// One 64-lane wave per segment. Lane r loads bucket element r (coalesced),
// wave-butterfly max gives maxt, per-lane weights, then the row-gather loop
// broadcasts idx/w via __shfl (no memory) and keeps 4 independent 1 KiB row
// loads in flight per batch.
__global__ void reduce_kernel(const float* __restrict__ msgs,
                              const int* __restrict__ sorted,
                              const float* __restrict__ sorted_t,
                              const int* __restrict__ offsets,
                              const int* __restrict__ counts,
                              float* __restrict__ agg,        // [S, D]
                              float* __restrict__ last_t_out, // [S]
                              int S) {
    int gid  = blockIdx.x * blockDim.x + threadIdx.x;
    int seg  = gid >> 6;
    int lane = threadIdx.x & 63;
    if (seg >= S) return;

    float4* orow = (float4*)(agg + (size_t)seg * D);
    int cnt = counts[seg];
    if (cnt == 0) {
        orow[lane] = make_float4(0.f, 0.f, 0.f, 0.f);
        if (lane == 0) last_t_out[seg] = 0.0f;
        return;
    }
    int start = offsets[seg];

    // pass A: wave-parallel max over bucket timestamps
    float tmax = -1e30f;
    for (int base = 0; base < cnt; base += 64) {
        int r = base + lane;
        float t = (r < cnt) ? sorted_t[start + r] : -1e30f;
        tmax = fmaxf(tmax, t);
    }
    #pragma unroll
    for (int off = 32; off > 0; off >>= 1)
        tmax = fmaxf(tmax, __shfl_xor(tmax, off));

    // pass B: weighted accumulate with batched row gathers
    float4 acc = make_float4(0.f, 0.f, 0.f, 0.f);
    float  tw  = 0.0f;
    for (int base = 0; base < cnt; base += 64) {
        int r    = base + lane;
        int tile = cnt - base; if (tile > 64) tile = 64;

        int   idx = 0;
        float w   = 0.0f;
        if (r < cnt) {
            idx = sorted[start + r];
            w   = __expf(BETA * (sorted_t[start + r] - tmax));  // (0,1]
            tw += w;
        }

        int j = 0;
        for (; j + 4 <= tile; j += 4) {
            int   i0 = __shfl(idx, j),     i1 = __shfl(idx, j + 1);
            int   i2 = __shfl(idx, j + 2), i3 = __shfl(idx, j + 3);
            float w0 = __shfl(w, j),       w1 = __shfl(w, j + 1);
            float w2 = __shfl(w, j + 2),   w3 = __shfl(w, j + 3);
            float4 m0 = ((const float4*)(msgs + (size_t)i0 * D))[lane];
            float4 m1 = ((const float4*)(msgs + (size_t)i1 * D))[lane];
            float4 m2 = ((const float4*)(msgs + (size_t)i2 * D))[lane];
            float4 m3 = ((const float4*)(msgs + (size_t)i3 * D))[lane];
            acc.x += m0.x * w0; acc.y += m0.y * w0; acc.z += m0.z * w0; acc.w += m0.w * w0;
            acc.x += m1.x * w1; acc.y += m1.y * w1; acc.z += m1.z * w1; acc.w += m1.w * w1;
            acc.x += m2.x * w2; acc.y += m2.y * w2; acc.z += m2.z * w2; acc.w += m2.w * w2;
            acc.x += m3.x * w3; acc.y += m3.y * w3; acc.z += m3.z * w3; acc.w += m3.w * w3;
        }
        for (; j < tile; ++j) {
            int   ib = __shfl(idx, j);
            float wb = __shfl(w, j);
            float4 m = ((const float4*)(msgs + (size_t)ib * D))[lane];
            acc.x += m.x * wb; acc.y += m.y * wb; acc.z += m.z * wb; acc.w += m.w * wb;
        }
    }

    // wave-sum of weights
    #pragma unroll
    for (int off = 32; off > 0; off >>= 1)
        tw += __shfl_xor(tw, off);

    float inv = 1.0f / tw;  // tw >= 1 (max element contributes exp(0)=1)
    orow[lane] = make_float4(acc.x * inv, acc.y * inv, acc.z * inv, acc.w * inv);
    if (lane == 0) last_t_out[seg] = tmax;
}

extern "C" void kernel_launch(void* const* d_in, const int* in_sizes, int n_in,
                              void* d_out, int out_size, void* d_ws, size_t ws_size,
                              hipStream_t stream) {
    const float* msgs = (const float*)d_in[0];
    const float* ts   = (const float*)d_in[1];
    const int*   node = (const int*)d_in[2];
    const int N = in_sizes[1];
    const int S = out_size / (D + 1);   // out = [S*D agg] + [S last_t]

    float* agg        = (float*)d_out;                  // [S, D]
    float* last_t_out = (float*)d_out + (size_t)S * D;  // [S]

    // workspace: counts[S] | offsets[S] | cursor[S] | sorted[N] | sorted_t[N]
    int*   counts   = (int*)d_ws;
    int*   offsets  = counts + S;
    int*   cursor   = offsets + S;
    int*   sorted   = cursor + S;
    float* sorted_t = (float*)(sorted + N);

    hipMemsetAsync(counts, 0, (size_t)S * sizeof(int), stream);

    hist_kernel<<<(N + 255) / 256, 256, 0, stream>>>(node, counts, N);
    scan_kernel<<<1, SCAN_T, 0, stream>>>(counts, offsets, cursor, S);
    scatter_kernel<<<(N + 255) / 256, 256, 0, stream>>>(node, ts, cursor,
                                                        sorted, sorted_t, N);

    long long threads = (long long)S * 64;
    reduce_kernel<<<(int)((threads + 255) / 256), 256, 0, stream>>>(
        msgs, sorted, sorted_t, offsets, counts, agg, last_t_out, S);
}